// Round 18
// baseline (334.172 us; speedup 1.0000x reference)
//
#include <hip/hip_runtime.h>
#include <cstdint>
#include <math.h>

typedef __bf16 bf16x8 __attribute__((ext_vector_type(8)));
typedef float f32x2 __attribute__((ext_vector_type(2)));
typedef float f32x4 __attribute__((ext_vector_type(4)));
typedef float f32x16 __attribute__((ext_vector_type(16)));
typedef int i32x2 __attribute__((ext_vector_type(2)));
typedef unsigned u32x4 __attribute__((ext_vector_type(4)));
typedef unsigned short u16;

#define B_ 4
#define N_ 2048
#define D_ 1024
#define H_ 16
#define DH_ 64
#define M_ (B_*N_)   // 8192

#define QSCALE (0.125f * 1.44269504088896f)   // 1/sqrt(Dh) * log2(e)

typedef const void __attribute__((address_space(1))) gvoid;
typedef void __attribute__((address_space(3))) lvoid;

__device__ __forceinline__ void gload16(const void* g, void* l) {
  __builtin_amdgcn_global_load_lds((gvoid*)g, (lvoid*)l, 16, 0, 0);
}

// hardware bf16 convert — do NOT hand-roll RNE (m240)
__device__ __forceinline__ u16 cvt_bf(float f) {
  __bf16 h = (__bf16)f;
  return *(u16*)&h;
}

// v_cvt_pk_bf16_f32: word = [bf16(lo) | bf16(hi)<<16]
__device__ __forceinline__ unsigned cvt_pk(float lo, float hi) {
  unsigned r;
  asm("v_cvt_pk_bf16_f32 %0, %1, %2" : "=v"(r) : "v"(lo), "v"(hi));
  return r;
}

__device__ __forceinline__ i32x2 pl32swap(unsigned a, unsigned b) {
  return __builtin_amdgcn_permlane32_swap((int)a, (int)b, false, false);
}

// packed f32 math (VOP3P)
__device__ __forceinline__ f32x2 pk_add(f32x2 a, f32x2 b) {
  f32x2 d;
  asm("v_pk_add_f32 %0, %1, %2" : "=v"(d) : "v"(a), "v"(b));
  return d;
}
__device__ __forceinline__ f32x2 pk_mul(f32x2 a, f32x2 b) {
  f32x2 d;
  asm("v_pk_mul_f32 %0, %1, %2" : "=v"(d) : "v"(a), "v"(b));
  return d;
}

// ---------------- weights-only cast fp32 -> bf16 ----------------
__global__ __launch_bounds__(256) void cast_w(
    const float* __restrict__ a, const float* __restrict__ b,
    const float* __restrict__ c, const float* __restrict__ e,
    u16* __restrict__ oa, u16* __restrict__ ob, u16* __restrict__ oc, u16* __restrict__ oe) {
  const int nw = (D_*D_)/4;
  int i = blockIdx.x * 256 + threadIdx.x;
  const float* s; u16* d;
  if (i < nw)        { s = a; d = oa; }
  else if (i < 2*nw) { s = b; d = ob; i -= nw; }
  else if (i < 3*nw) { s = c; d = oc; i -= 2*nw; }
  else               { s = e; d = oe; i -= 3*nw; }
  float4 x = ((const float4*)s)[i];
  ushort4 y;
  y.x = cvt_bf(x.x); y.y = cvt_bf(x.y); y.z = cvt_bf(x.z); y.w = cvt_bf(x.w);
  ((ushort4*)d)[i] = y;
}

// ------ QKV projection GEMM: A direct-from-global (no A LDS), BK=64 ------
// A fragments read straight from global into regs (L2/L3-resident; lanes of
// a quarter-wave hit 16 distinct 64B lines = minimal), cvt_pk in regs.
// Only W goes through LDS (16KB, swizzled). Halves LDS-read traffic and
// shrinks the barrier-drained staging 48KB->16KB.
// z=0: Q (scaled); z=1: K; z=2: V pre-transposed.
__global__ __launch_bounds__(256) void gemm_qkv(
    const float* __restrict__ Aq, const float* __restrict__ Ak, const float* __restrict__ Av,
    const u16* __restrict__ Wq, const u16* __restrict__ Wk, const u16* __restrict__ Wv,
    u16* __restrict__ Oq, u16* __restrict__ Ok, u16* __restrict__ Ov)
{
  __shared__ __align__(16) u16 Bs[128*64];       // 16KB bf16 W tile
  const int z = blockIdx.z;
  const float* A = (z == 0) ? Aq : (z == 1) ? Ak : Av;
  const u16* W  = (z == 0) ? Wq : (z == 1) ? Wk : Wv;
  u16* obf      = (z == 0) ? Oq : (z == 1) ? Ok : Ov;
  const float oscale = (z == 0) ? QSCALE : 1.0f;

  const int t = threadIdx.x;
  const int lane = t & 63;
  const int w = t >> 6;
  const int wr = w >> 1, wc = w & 1;
  const int m0 = blockIdx.x * 128;
  const int n0 = blockIdx.y * 128;
  f32x4 acc[4][4] = {};

  // W staging (8-block swizzle, linear LDS dest)
  const int srow = t >> 3;              // + p*32
  const int scb = (t & 7) ^ (srow & 7);
  const u16* wsrc = W + (size_t)(n0 + srow)*1024 + scb*8;

  const int fr = lane & 15;
  const int fg = lane >> 4;
  const int fs7 = fr & 7;

  // A fragment base: rows m0 + wr*64 + i*16 + fr, cols k0 + (ks*4+fg)*8
  const float* abase = A + (size_t)(m0 + wr*64 + fr)*1024 + fg*8;

  for (int k0 = 0; k0 < 1024; k0 += 64) {
#pragma unroll
    for (int p = 0; p < 4; ++p)
      gload16(wsrc + (size_t)(p*32)*1024 + k0, &Bs[(p*256 + t)*8]);
    // A: direct global -> regs (16 x dwordx4), overlaps the W-stage drain
    f32x4 a[4][2][2];
#pragma unroll
    for (int i = 0; i < 4; ++i)
#pragma unroll
      for (int ks = 0; ks < 2; ++ks) {
        const float* s = abase + (size_t)(i*16)*1024 + k0 + ks*32;
        a[i][ks][0] = *(const f32x4*)s;
        a[i][ks][1] = *(const f32x4*)(s + 4);
      }
    __syncthreads();
#pragma unroll
    for (int ks = 0; ks < 2; ++ks) {
      bf16x8 af[4], bfr[4];
#pragma unroll
      for (int i = 0; i < 4; ++i) {
        u32x4 pk = { cvt_pk(a[i][ks][0].x, a[i][ks][0].y),
                     cvt_pk(a[i][ks][0].z, a[i][ks][0].w),
                     cvt_pk(a[i][ks][1].x, a[i][ks][1].y),
                     cvt_pk(a[i][ks][1].z, a[i][ks][1].w) };
        af[i] = __builtin_bit_cast(bf16x8, pk);
        int rb = wc*64 + i*16 + fr;
        bfr[i] = *(const bf16x8*)&Bs[rb*64 + (((ks*4 + fg) ^ fs7) * 8)];
      }
#pragma unroll
      for (int i = 0; i < 4; ++i)
#pragma unroll
        for (int j = 0; j < 4; ++j)
          acc[i][j] = __builtin_amdgcn_mfma_f32_16x16x32_bf16(af[i], bfr[j], acc[i][j], 0, 0, 0);
    }
    __syncthreads();
  }

#pragma unroll
  for (int i = 0; i < 4; ++i) {
#pragma unroll
    for (int j = 0; j < 4; ++j) {
#pragma unroll
      for (int jj = 0; jj < 4; ++jj) {
        int row = m0 + wr*64 + i*16 + fg*4 + jj;   // verified C/D layout
        int col = n0 + wc*64 + j*16 + fr;
        float val = acc[i][j][jj];
        int b = row >> 11, n = row & 2047, h = col >> 6, dh = col & 63;
        if (z != 2) {
          obf[(((size_t)(b*H_ + h))*N_ + n)*DH_ + dh] = cvt_bf(val * oscale);
        } else {
          obf[(((size_t)(b*H_ + h))*DH_ + dh)*N_ + n] = cvt_bf(val);
        }
      }
    }
  }
}

// ---------------- output projection GEMM + residual, BK=64 ---------------
__global__ __launch_bounds__(256) void gemm_out(
    const u16* __restrict__ A, const u16* __restrict__ W,
    const float* __restrict__ resid, float* __restrict__ ofp)
{
  __shared__ __align__(16) u16 As[128*64];
  __shared__ __align__(16) u16 Bs[128*64];
  const int t = threadIdx.x;
  const int lane = t & 63;
  const int w = t >> 6;
  const int wr = w >> 1, wc = w & 1;
  const int m0 = blockIdx.x * 128;
  const int n0 = blockIdx.y * 128;
  f32x4 acc[4][4] = {};

  const int srow = t >> 3;
  const int scb = (t & 7) ^ (srow & 7);
  const int fr = lane & 15;
  const int fg = lane >> 4;
  const int fs7 = fr & 7;

  for (int k0 = 0; k0 < 1024; k0 += 64) {
#pragma unroll
    for (int p = 0; p < 4; ++p) {
      int r = p*32 + srow;
      gload16(A + (size_t)(m0 + r)*1024 + k0 + scb*8, &As[(p*256 + t)*8]);
      gload16(W + (size_t)(n0 + r)*1024 + k0 + scb*8, &Bs[(p*256 + t)*8]);
    }
    __syncthreads();
#pragma unroll
    for (int ks = 0; ks < 2; ++ks) {
      bf16x8 af[4], bfr[4];
#pragma unroll
      for (int i = 0; i < 4; ++i) {
        int ra = wr*64 + i*16 + fr;
        af[i]  = *(const bf16x8*)&As[ra*64 + (((ks*4 + fg) ^ fs7) * 8)];
        int rb = wc*64 + i*16 + fr;
        bfr[i] = *(const bf16x8*)&Bs[rb*64 + (((ks*4 + fg) ^ fs7) * 8)];
      }
#pragma unroll
      for (int i = 0; i < 4; ++i)
#pragma unroll
        for (int j = 0; j < 4; ++j)
          acc[i][j] = __builtin_amdgcn_mfma_f32_16x16x32_bf16(af[i], bfr[j], acc[i][j], 0, 0, 0);
    }
    __syncthreads();
  }

#pragma unroll
  for (int i = 0; i < 4; ++i)
#pragma unroll
    for (int j = 0; j < 4; ++j)
#pragma unroll
      for (int jj = 0; jj < 4; ++jj) {
        int row = m0 + wr*64 + i*16 + fg*4 + jj;
        int col = n0 + wc*64 + j*16 + fr;
        size_t idx = (size_t)row*1024 + col;
        ofp[idx] = acc[i][j][jj] + resid[idx];
      }
}

// ---------------- flash attention: 64 q/wave, KVBLK=128, no-max exp2 -----
// grid (B*H=64, N/256=8); block 256 = 4 waves; wave w owns q-rows q0+w*64.
// NO setprio; V-frags hoisted before softmax. (R12 — wall-best)
__device__ __forceinline__ f32x2 sp2(const f32x16& S, int i) {
  f32x2 r; r.x = S[2*i]; r.y = S[2*i + 1]; return r;
}
__device__ __forceinline__ void exp2v(f32x16& S) {
#pragma unroll
  for (int r = 0; r < 16; ++r) S[r] = __builtin_amdgcn_exp2f(S[r]);
}
__device__ __forceinline__ f32x2 sumtree(const f32x16& S0, const f32x16& S1) {
  f32x2 a0 = pk_add(sp2(S0,0), sp2(S0,1));
  f32x2 a1 = pk_add(sp2(S0,2), sp2(S0,3));
  f32x2 a2 = pk_add(sp2(S0,4), sp2(S0,5));
  f32x2 a3 = pk_add(sp2(S0,6), sp2(S0,7));
  f32x2 b0 = pk_add(sp2(S1,0), sp2(S1,1));
  f32x2 b1 = pk_add(sp2(S1,2), sp2(S1,3));
  f32x2 b2 = pk_add(sp2(S1,4), sp2(S1,5));
  f32x2 b3 = pk_add(sp2(S1,6), sp2(S1,7));
  a0 = pk_add(a0, a1); a2 = pk_add(a2, a3);
  b0 = pk_add(b0, b1); b2 = pk_add(b2, b3);
  a0 = pk_add(a0, a2); b0 = pk_add(b0, b2);
  return pk_add(a0, b0);
}
// P^T B-frag assembly (T12)
__device__ __forceinline__ void buildP(const f32x16& S, bf16x8* pf) {
  unsigned w0 = cvt_pk(S[0], S[1]),  w1 = cvt_pk(S[2], S[3]);
  unsigned w2 = cvt_pk(S[4], S[5]),  w3 = cvt_pk(S[6], S[7]);
  i32x2 A2 = pl32swap(w0, w2), B2 = pl32swap(w1, w3);
  u32x4 f0 = { (unsigned)A2.x, (unsigned)B2.x, (unsigned)A2.y, (unsigned)B2.y };
  pf[0] = __builtin_bit_cast(bf16x8, f0);
  unsigned w4 = cvt_pk(S[8], S[9]),   w5 = cvt_pk(S[10], S[11]);
  unsigned w6 = cvt_pk(S[12], S[13]), w7 = cvt_pk(S[14], S[15]);
  i32x2 C2 = pl32swap(w4, w6), D2 = pl32swap(w5, w7);
  u32x4 f1 = { (unsigned)C2.x, (unsigned)D2.x, (unsigned)C2.y, (unsigned)D2.y };
  pf[1] = __builtin_bit_cast(bf16x8, f1);
}

__global__ __launch_bounds__(256, 2) void flash_attn(
    const u16* __restrict__ Qs, const u16* __restrict__ Ks,
    const u16* __restrict__ VTs, u16* __restrict__ ctx)
{
  __shared__ __align__(16) u16 Klds[2][128*64];   // [k 0..127][d 0..63]
  __shared__ __align__(16) u16 Vlds[2][64*128];   // [d 0..63][k 0..127]
  const int t = threadIdx.x;
  const int lane = t & 63;
  const int w = t >> 6;         // 0..3
  const int l31 = lane & 31;
  const int h = lane >> 5;      // half-wave
  const int bh = blockIdx.x;
  const int q0 = blockIdx.y * 256 + w * 64;
  const u16* Qbh = Qs  + (size_t)bh * N_ * DH_;
  const u16* Kbh = Ks  + (size_t)bh * N_ * DH_;
  const u16* Vbh = VTs + (size_t)bh * DH_ * N_;

  // Q B-frags for both 32-row halves
  bf16x8 qfA[4], qfB[4];
#pragma unroll
  for (int dd = 0; dd < 4; ++dd) {
    qfA[dd] = *(const bf16x8*)&Qbh[(size_t)(q0 + l31)*64 + dd*16 + h*8];
    qfB[dd] = *(const bf16x8*)&Qbh[(size_t)(q0 + 32 + l31)*64 + dd*16 + h*8];
  }

  f32x2 lA = {0.f, 0.f}, lB = {0.f, 0.f};
  f32x16 OA0 = {}, OA1 = {}, OB0 = {}, OB1 = {};

  // staging: K 4 passes (32 rows each), V 4 passes (16 rows each)
  const int krow = t >> 3;                        // 0..31 (+p*32)
  const int kcb  = (t & 7) ^ (krow & 7);          // 8-block swizzle (64 cols)
  const int vrow = t >> 4;                        // 0..15 (+p*16)
  const int vcb  = (t & 15) ^ vrow;               // 16-block swizzle (128 cols)
  const u16* ksrc = Kbh + (size_t)krow*64 + kcb*8;
  const u16* vsrc = Vbh + (size_t)vrow*N_ + vcb*8;

  auto stage = [&](int buf, int kv) {
#pragma unroll
    for (int p = 0; p < 4; ++p)
      gload16(ksrc + (size_t)(kv + p*32)*64, &Klds[buf][(p*256 + t)*8]);
#pragma unroll
    for (int p = 0; p < 4; ++p)
      gload16(vsrc + kv + (size_t)(p*16)*N_, &Vlds[buf][(p*256 + t)*8]);
  };

  const int l7 = l31 & 7;
  const int l15 = l31 & 15;

  stage(0, 0);
  __syncthreads();
  int cur = 0;

  for (int kv0 = 0; kv0 < N_; kv0 += 128) {
    if (kv0 + 128 < N_) stage(cur ^ 1, kv0 + 128);

#pragma unroll
    for (int c = 0; c < 2; ++c) {
      const int kb = c * 64;
      // K fragments once, reused for both q-halves
      bf16x8 kf0[4], kf1[4];
#pragma unroll
      for (int dd = 0; dd < 4; ++dd) {
        int cb = ((dd*2 + h) ^ l7) * 8;
        kf0[dd] = *(const bf16x8*)&Klds[cur][(kb + l31)*64 + cb];
        kf1[dd] = *(const bf16x8*)&Klds[cur][(kb + 32 + l31)*64 + cb];
      }
      // V fragments hoisted: lgkmcnt overlaps QK MFMA issue
      bf16x8 vf0[4], vf1[4];
#pragma unroll
      for (int ks = 0; ks < 4; ++ks) {
        int kc = (c*8 + ks*2 + h) ^ l15;
        vf0[ks] = *(const bf16x8*)&Vlds[cur][l31*128 + kc*8];
        vf1[ks] = *(const bf16x8*)&Vlds[cur][(32 + l31)*128 + kc*8];
      }

      f32x16 SA0 = {}, SA1 = {}, SB0 = {}, SB1 = {};
#pragma unroll
      for (int dd = 0; dd < 4; ++dd) {
        SA0 = __builtin_amdgcn_mfma_f32_32x32x16_bf16(kf0[dd], qfA[dd], SA0, 0, 0, 0);
        SA1 = __builtin_amdgcn_mfma_f32_32x32x16_bf16(kf1[dd], qfA[dd], SA1, 0, 0, 0);
      }
#pragma unroll
      for (int dd = 0; dd < 4; ++dd) {
        SB0 = __builtin_amdgcn_mfma_f32_32x32x16_bf16(kf0[dd], qfB[dd], SB0, 0, 0, 0);
        SB1 = __builtin_amdgcn_mfma_f32_32x32x16_bf16(kf1[dd], qfB[dd], SB1, 0, 0, 0);
      }

      // half A: exp2 direct (no max), build P frags
      exp2v(SA0); exp2v(SA1);
      bf16x8 pfA[4];
      buildP(SA0, &pfA[0]);
      buildP(SA1, &pfA[2]);

#pragma unroll
      for (int ks = 0; ks < 4; ++ks) {
        OA0 = __builtin_amdgcn_mfma_f32_32x32x16_bf16(vf0[ks], pfA[ks], OA0, 0, 0, 0);
        OA1 = __builtin_amdgcn_mfma_f32_32x32x16_bf16(vf1[ks], pfA[ks], OA1, 0, 0, 0);
      }
      lA = pk_add(lA, sumtree(SA0, SA1));   // after PV-A issue

      // half B
      exp2v(SB0); exp2v(SB1);
      bf16x8 pfB[4];
      buildP(SB0, &pfB[0]);
      buildP(SB1, &pfB[2]);
#pragma unroll
      for (int ks = 0; ks < 4; ++ks) {
        OB0 = __builtin_amdgcn_mfma_f32_32x32x16_bf16(vf0[ks], pfB[ks], OB0, 0, 0, 0);
        OB1 = __builtin_amdgcn_mfma_f32_32x32x16_bf16(vf1[ks], pfB[ks], OB1, 0, 0, 0);
      }
      lB = pk_add(lB, sumtree(SB0, SB1));
    }

    __syncthreads();   // all waves done with [cur]; prefetch landed
    cur ^= 1;
  }

  // epilogue: per-half l combine + write ctx [B,N,D] bf16
  int b = bh >> 4, hh = bh & 15;
  {
    float lps = lA.x + lA.y;
    i32x2 lsw = pl32swap(__float_as_uint(lps), __float_as_uint(lps));
    float ltot = __uint_as_float((unsigned)lsw.x) + __uint_as_float((unsigned)lsw.y);
    float linv = __builtin_amdgcn_rcpf(ltot);
    f32x2 li2; li2.x = linv; li2.y = linv;
    unsigned* crow = (unsigned*)(ctx + ((size_t)b*N_ + (q0 + l31))*D_ + hh*64);
#pragma unroll
    for (int rp = 0; rp < 8; ++rp) {
      int r = rp*2;
      int d0 = (r & 3) + 8*(r >> 2) + 4*h;
      f32x2 o0 = pk_mul(sp2(OA0, rp), li2);
      f32x2 o1 = pk_mul(sp2(OA1, rp), li2);
      crow[d0 >> 1]        = cvt_pk(o0.x, o0.y);
      crow[(d0 + 32) >> 1] = cvt_pk(o1.x, o1.y);
    }
  }
  {
    float lps = lB.x + lB.y;
    i32x2 lsw = pl32swap(__float_as_uint(lps), __float_as_uint(lps));
    float ltot = __uint_as_float((unsigned)lsw.x) + __uint_as_float((unsigned)lsw.y);
    float linv = __builtin_amdgcn_rcpf(ltot);
    f32x2 li2; li2.x = linv; li2.y = linv;
    unsigned* crow = (unsigned*)(ctx + ((size_t)b*N_ + (q0 + 32 + l31))*D_ + hh*64);
#pragma unroll
    for (int rp = 0; rp < 8; ++rp) {
      int r = rp*2;
      int d0 = (r & 3) + 8*(r >> 2) + 4*h;
      f32x2 o0 = pk_mul(sp2(OB0, rp), li2);
      f32x2 o1 = pk_mul(sp2(OB1, rp), li2);
      crow[d0 >> 1]        = cvt_pk(o0.x, o0.y);
      crow[(d0 + 32) >> 1] = cvt_pk(o1.x, o1.y);
    }
  }
}

// ---------------- LayerNorm in-place on d_out ----------------
__global__ __launch_bounds__(256) void ln_fwd(float* __restrict__ io,
    const float* __restrict__ gamma, const float* __restrict__ beta)
{
  __shared__ float red[4];
  const int t = threadIdx.x;
  const int lane = t & 63, w = t >> 6;
  float4* row = (float4*)(io + (size_t)blockIdx.x * 1024);
  float4 x = row[t];
  float s = x.x + x.y + x.z + x.w;
#pragma unroll
  for (int m = 1; m < 64; m <<= 1) s += __shfl_xor(s, m);
  if (lane == 0) red[w] = s;
  __syncthreads();
  float mean = (red[0] + red[1] + red[2] + red[3]) * (1.f/1024.f);
  __syncthreads();
  float dx0 = x.x - mean, dx1 = x.y - mean, dx2 = x.z - mean, dx3 = x.w - mean;
  float sq = dx0*dx0 + dx1*dx1 + dx2*dx2 + dx3*dx3;
#pragma unroll
  for (int m = 1; m < 64; m <<= 1) sq += __shfl_xor(sq, m);
  if (lane == 0) red[w] = sq;
  __syncthreads();
  float var = (red[0] + red[1] + red[2] + red[3]) * (1.f/1024.f);
  float rstd = rsqrtf(var + 1e-5f);
  float4 g = ((const float4*)gamma)[t];
  float4 bb = ((const float4*)beta)[t];
  float4 y;
  y.x = dx0*rstd*g.x + bb.x;
  y.y = dx1*rstd*g.y + bb.y;
  y.z = dx2*rstd*g.z + bb.z;
  y.w = dx3*rstd*g.w + bb.w;
  row[t] = y;
}

extern "C" void kernel_launch(void* const* d_in, const int* in_sizes, int n_in,
                              void* d_out, int out_size, void* d_ws, size_t ws_size,
                              hipStream_t stream) {
  const float* q     = (const float*)d_in[0];
  const float* k     = (const float*)d_in[1];
  const float* v     = (const float*)d_in[2];
  const float* Wq    = (const float*)d_in[3];
  const float* Wk    = (const float*)d_in[4];
  const float* Wv    = (const float*)d_in[5];
  const float* Wo    = (const float*)d_in[6];
  const float* gamma = (const float*)d_in[7];
  const float* beta  = (const float*)d_in[8];
  float* out = (float*)d_out;

  char* ws = (char*)d_ws;
  const size_t MB = 1024*1024;
  u16* Wqb = (u16*)(ws + 0*MB);    // 2 MB each
  u16* Wkb = (u16*)(ws + 2*MB);
  u16* Wvb = (u16*)(ws + 4*MB);
  u16* Wob = (u16*)(ws + 6*MB);
  u16* Qs  = (u16*)(ws + 8*MB);    // [B,H,N,Dh] bf16 (pre-scaled by QSCALE)
  u16* Ks  = (u16*)(ws + 24*MB);   // [B,H,N,Dh]
  u16* VTs = (u16*)(ws + 40*MB);   // [B,H,Dh,N]
  u16* ctx = (u16*)(ws + 56*MB);   // [B,N,D] bf16

  const int nw4 = 4*((D_*D_)/4);   // 1M float4s
  cast_w<<<nw4/256, 256, 0, stream>>>(Wq, Wk, Wv, Wo, Wqb, Wkb, Wvb, Wob);

  dim3 gproj(M_/128, D_/128, 3);   // (64, 8, 3)
  gemm_qkv<<<gproj, 256, 0, stream>>>(q, k, v, Wqb, Wkb, Wvb, Qs, Ks, VTs);

  flash_attn<<<dim3(B_*H_, N_/256), 256, 0, stream>>>(Qs, Ks, VTs, ctx);

  gemm_out<<<dim3(M_/128, D_/128), 256, 0, stream>>>(ctx, Wob, q, out);

  ln_fwd<<<M_, 256, 0, stream>>>(out, gamma, beta);
}

// Round 19
// 209.435 us; speedup vs baseline: 1.5956x; 1.5956x over previous
//
#include <hip/hip_runtime.h>
#include <cstdint>
#include <math.h>

typedef __bf16 bf16x8 __attribute__((ext_vector_type(8)));
typedef float f32x2 __attribute__((ext_vector_type(2)));
typedef float f32x4 __attribute__((ext_vector_type(4)));
typedef float f32x16 __attribute__((ext_vector_type(16)));
typedef int i32x2 __attribute__((ext_vector_type(2)));
typedef unsigned u32x4 __attribute__((ext_vector_type(4)));
typedef unsigned short u16;

#define B_ 4
#define N_ 2048
#define D_ 1024
#define H_ 16
#define DH_ 64
#define M_ (B_*N_)   // 8192

#define QSCALE (0.125f * 1.44269504088896f)   // 1/sqrt(Dh) * log2(e)

typedef const void __attribute__((address_space(1))) gvoid;
typedef void __attribute__((address_space(3))) lvoid;

__device__ __forceinline__ void gload16(const void* g, void* l) {
  __builtin_amdgcn_global_load_lds((gvoid*)g, (lvoid*)l, 16, 0, 0);
}

// hardware bf16 convert — do NOT hand-roll RNE (m240)
__device__ __forceinline__ u16 cvt_bf(float f) {
  __bf16 h = (__bf16)f;
  return *(u16*)&h;
}

// v_cvt_pk_bf16_f32: word = [bf16(lo) | bf16(hi)<<16]
__device__ __forceinline__ unsigned cvt_pk(float lo, float hi) {
  unsigned r;
  asm("v_cvt_pk_bf16_f32 %0, %1, %2" : "=v"(r) : "v"(lo), "v"(hi));
  return r;
}

__device__ __forceinline__ i32x2 pl32swap(unsigned a, unsigned b) {
  return __builtin_amdgcn_permlane32_swap((int)a, (int)b, false, false);
}

// packed f32 math (VOP3P)
__device__ __forceinline__ f32x2 pk_add(f32x2 a, f32x2 b) {
  f32x2 d;
  asm("v_pk_add_f32 %0, %1, %2" : "=v"(d) : "v"(a), "v"(b));
  return d;
}
__device__ __forceinline__ f32x2 pk_mul(f32x2 a, f32x2 b) {
  f32x2 d;
  asm("v_pk_mul_f32 %0, %1, %2" : "=v"(d) : "v"(a), "v"(b));
  return d;
}

// ---------------- weights-only cast fp32 -> bf16 ----------------
__global__ __launch_bounds__(256) void cast_w(
    const float* __restrict__ a, const float* __restrict__ b,
    const float* __restrict__ c, const float* __restrict__ e,
    u16* __restrict__ oa, u16* __restrict__ ob, u16* __restrict__ oc, u16* __restrict__ oe) {
  const int nw = (D_*D_)/4;
  int i = blockIdx.x * 256 + threadIdx.x;
  const float* s; u16* d;
  if (i < nw)        { s = a; d = oa; }
  else if (i < 2*nw) { s = b; d = ob; i -= nw; }
  else if (i < 3*nw) { s = c; d = oc; i -= 2*nw; }
  else               { s = e; d = oe; i -= 3*nw; }
  float4 x = ((const float4*)s)[i];
  ushort4 y;
  y.x = cvt_bf(x.x); y.y = cvt_bf(x.y); y.z = cvt_bf(x.z); y.w = cvt_bf(x.w);
  ((ushort4*)d)[i] = y;
}

// ---------------- QKV projection GEMM: fp32 A direct, BK=64, z=3 ---------
// (R12 config — wall-best) A fp32 via global_load_lds into 32KB LDS tile
// (16-block XOR swizzle), cvt to bf16 at fragment-read. W bf16 16KB.
// z=0: Q (scaled); z=1: K; z=2: V pre-transposed.
__global__ __launch_bounds__(256) void gemm_qkv(
    const float* __restrict__ Aq, const float* __restrict__ Ak, const float* __restrict__ Av,
    const u16* __restrict__ Wq, const u16* __restrict__ Wk, const u16* __restrict__ Wv,
    u16* __restrict__ Oq, u16* __restrict__ Ok, u16* __restrict__ Ov)
{
  __shared__ __align__(16) float As32[128*64];   // 32KB fp32 A tile
  __shared__ __align__(16) u16 Bs[128*64];       // 16KB bf16 W tile
  const int z = blockIdx.z;
  const float* A = (z == 0) ? Aq : (z == 1) ? Ak : Av;
  const u16* W  = (z == 0) ? Wq : (z == 1) ? Wk : Wv;
  u16* obf      = (z == 0) ? Oq : (z == 1) ? Ok : Ov;
  const float oscale = (z == 0) ? QSCALE : 1.0f;

  const int t = threadIdx.x;
  const int lane = t & 63;
  const int w = t >> 6;
  const int wr = w >> 1, wc = w & 1;
  const int m0 = blockIdx.x * 128;
  const int n0 = blockIdx.y * 128;
  f32x4 acc[4][4] = {};

  // W staging (8-block swizzle)
  const int srow = t >> 3;              // + p*32
  const int scb = (t & 7) ^ (srow & 7);
  // A fp32 staging: 16-block (16B = 4 float) swizzle with row&15
  const int arow = t >> 4;              // 0..15 (+p*16)
  const int asb  = (t & 15) ^ arow;

  const int fr = lane & 15;
  const int fg = lane >> 4;
  const int fs7 = fr & 7;

  for (int k0 = 0; k0 < 1024; k0 += 64) {
#pragma unroll
    for (int p = 0; p < 4; ++p)
      gload16(W + (size_t)(n0 + p*32 + srow)*1024 + k0 + scb*8, &Bs[(p*256 + t)*8]);
#pragma unroll
    for (int p = 0; p < 8; ++p)
      gload16(A + (size_t)(m0 + p*16 + arow)*1024 + k0 + asb*4, &As32[(p*256 + t)*4]);
    __syncthreads();
#pragma unroll
    for (int ks = 0; ks < 2; ++ks) {
      bf16x8 af[4], bfr[4];
#pragma unroll
      for (int i = 0; i < 4; ++i) {
        int ra = wr*64 + i*16 + fr;
        int b0 = (ks*4 + fg) * 2;
        int r15 = ra & 15;
        f32x4 lo = *(const f32x4*)&As32[ra*64 + ((b0 ^ r15) * 4)];
        f32x4 hi = *(const f32x4*)&As32[ra*64 + (((b0 + 1) ^ r15) * 4)];
        u32x4 pk = { cvt_pk(lo.x, lo.y), cvt_pk(lo.z, lo.w),
                     cvt_pk(hi.x, hi.y), cvt_pk(hi.z, hi.w) };
        af[i] = __builtin_bit_cast(bf16x8, pk);
        int rb = wc*64 + i*16 + fr;
        bfr[i] = *(const bf16x8*)&Bs[rb*64 + (((ks*4 + fg) ^ fs7) * 8)];
      }
#pragma unroll
      for (int i = 0; i < 4; ++i)
#pragma unroll
        for (int j = 0; j < 4; ++j)
          acc[i][j] = __builtin_amdgcn_mfma_f32_16x16x32_bf16(af[i], bfr[j], acc[i][j], 0, 0, 0);
    }
    __syncthreads();
  }

#pragma unroll
  for (int i = 0; i < 4; ++i) {
#pragma unroll
    for (int j = 0; j < 4; ++j) {
#pragma unroll
      for (int jj = 0; jj < 4; ++jj) {
        int row = m0 + wr*64 + i*16 + fg*4 + jj;   // verified C/D layout
        int col = n0 + wc*64 + j*16 + fr;
        float val = acc[i][j][jj];
        int b = row >> 11, n = row & 2047, h = col >> 6, dh = col & 63;
        if (z != 2) {
          obf[(((size_t)(b*H_ + h))*N_ + n)*DH_ + dh] = cvt_bf(val * oscale);
        } else {
          obf[(((size_t)(b*H_ + h))*DH_ + dh)*N_ + n] = cvt_bf(val);
        }
      }
    }
  }
}

// ---------------- output projection GEMM + residual, BK=64 ---------------
__global__ __launch_bounds__(256) void gemm_out(
    const u16* __restrict__ A, const u16* __restrict__ W,
    const float* __restrict__ resid, float* __restrict__ ofp)
{
  __shared__ __align__(16) u16 As[128*64];
  __shared__ __align__(16) u16 Bs[128*64];
  const int t = threadIdx.x;
  const int lane = t & 63;
  const int w = t >> 6;
  const int wr = w >> 1, wc = w & 1;
  const int m0 = blockIdx.x * 128;
  const int n0 = blockIdx.y * 128;
  f32x4 acc[4][4] = {};

  const int srow = t >> 3;
  const int scb = (t & 7) ^ (srow & 7);
  const int fr = lane & 15;
  const int fg = lane >> 4;
  const int fs7 = fr & 7;

  for (int k0 = 0; k0 < 1024; k0 += 64) {
#pragma unroll
    for (int p = 0; p < 4; ++p) {
      int r = p*32 + srow;
      gload16(A + (size_t)(m0 + r)*1024 + k0 + scb*8, &As[(p*256 + t)*8]);
      gload16(W + (size_t)(n0 + r)*1024 + k0 + scb*8, &Bs[(p*256 + t)*8]);
    }
    __syncthreads();
#pragma unroll
    for (int ks = 0; ks < 2; ++ks) {
      bf16x8 af[4], bfr[4];
#pragma unroll
      for (int i = 0; i < 4; ++i) {
        int ra = wr*64 + i*16 + fr;
        af[i]  = *(const bf16x8*)&As[ra*64 + (((ks*4 + fg) ^ fs7) * 8)];
        int rb = wc*64 + i*16 + fr;
        bfr[i] = *(const bf16x8*)&Bs[rb*64 + (((ks*4 + fg) ^ fs7) * 8)];
      }
#pragma unroll
      for (int i = 0; i < 4; ++i)
#pragma unroll
        for (int j = 0; j < 4; ++j)
          acc[i][j] = __builtin_amdgcn_mfma_f32_16x16x32_bf16(af[i], bfr[j], acc[i][j], 0, 0, 0);
    }
    __syncthreads();
  }

#pragma unroll
  for (int i = 0; i < 4; ++i)
#pragma unroll
    for (int j = 0; j < 4; ++j)
#pragma unroll
      for (int jj = 0; jj < 4; ++jj) {
        int row = m0 + wr*64 + i*16 + fg*4 + jj;
        int col = n0 + wc*64 + j*16 + fr;
        size_t idx = (size_t)row*1024 + col;
        ofp[idx] = acc[i][j][jj] + resid[idx];
      }
}

// ---------------- flash attention: 64 q/wave, KVBLK=128, no-max exp2 -----
// grid (B*H=64, N/256=8); block 256 = 4 waves; wave w owns q-rows q0+w*64.
// NO setprio; V-frags hoisted before softmax. (R12 — wall-best)
__device__ __forceinline__ f32x2 sp2(const f32x16& S, int i) {
  f32x2 r; r.x = S[2*i]; r.y = S[2*i + 1]; return r;
}
__device__ __forceinline__ void exp2v(f32x16& S) {
#pragma unroll
  for (int r = 0; r < 16; ++r) S[r] = __builtin_amdgcn_exp2f(S[r]);
}
__device__ __forceinline__ f32x2 sumtree(const f32x16& S0, const f32x16& S1) {
  f32x2 a0 = pk_add(sp2(S0,0), sp2(S0,1));
  f32x2 a1 = pk_add(sp2(S0,2), sp2(S0,3));
  f32x2 a2 = pk_add(sp2(S0,4), sp2(S0,5));
  f32x2 a3 = pk_add(sp2(S0,6), sp2(S0,7));
  f32x2 b0 = pk_add(sp2(S1,0), sp2(S1,1));
  f32x2 b1 = pk_add(sp2(S1,2), sp2(S1,3));
  f32x2 b2 = pk_add(sp2(S1,4), sp2(S1,5));
  f32x2 b3 = pk_add(sp2(S1,6), sp2(S1,7));
  a0 = pk_add(a0, a1); a2 = pk_add(a2, a3);
  b0 = pk_add(b0, b1); b2 = pk_add(b2, b3);
  a0 = pk_add(a0, a2); b0 = pk_add(b0, b2);
  return pk_add(a0, b0);
}
// P^T B-frag assembly (T12)
__device__ __forceinline__ void buildP(const f32x16& S, bf16x8* pf) {
  unsigned w0 = cvt_pk(S[0], S[1]),  w1 = cvt_pk(S[2], S[3]);
  unsigned w2 = cvt_pk(S[4], S[5]),  w3 = cvt_pk(S[6], S[7]);
  i32x2 A2 = pl32swap(w0, w2), B2 = pl32swap(w1, w3);
  u32x4 f0 = { (unsigned)A2.x, (unsigned)B2.x, (unsigned)A2.y, (unsigned)B2.y };
  pf[0] = __builtin_bit_cast(bf16x8, f0);
  unsigned w4 = cvt_pk(S[8], S[9]),   w5 = cvt_pk(S[10], S[11]);
  unsigned w6 = cvt_pk(S[12], S[13]), w7 = cvt_pk(S[14], S[15]);
  i32x2 C2 = pl32swap(w4, w6), D2 = pl32swap(w5, w7);
  u32x4 f1 = { (unsigned)C2.x, (unsigned)D2.x, (unsigned)C2.y, (unsigned)D2.y };
  pf[1] = __builtin_bit_cast(bf16x8, f1);
}

__global__ __launch_bounds__(256, 2) void flash_attn(
    const u16* __restrict__ Qs, const u16* __restrict__ Ks,
    const u16* __restrict__ VTs, u16* __restrict__ ctx)
{
  __shared__ __align__(16) u16 Klds[2][128*64];   // [k 0..127][d 0..63]
  __shared__ __align__(16) u16 Vlds[2][64*128];   // [d 0..63][k 0..127]
  const int t = threadIdx.x;
  const int lane = t & 63;
  const int w = t >> 6;         // 0..3
  const int l31 = lane & 31;
  const int h = lane >> 5;      // half-wave
  const int bh = blockIdx.x;
  const int q0 = blockIdx.y * 256 + w * 64;
  const u16* Qbh = Qs  + (size_t)bh * N_ * DH_;
  const u16* Kbh = Ks  + (size_t)bh * N_ * DH_;
  const u16* Vbh = VTs + (size_t)bh * DH_ * N_;

  // Q B-frags for both 32-row halves
  bf16x8 qfA[4], qfB[4];
#pragma unroll
  for (int dd = 0; dd < 4; ++dd) {
    qfA[dd] = *(const bf16x8*)&Qbh[(size_t)(q0 + l31)*64 + dd*16 + h*8];
    qfB[dd] = *(const bf16x8*)&Qbh[(size_t)(q0 + 32 + l31)*64 + dd*16 + h*8];
  }

  f32x2 lA = {0.f, 0.f}, lB = {0.f, 0.f};
  f32x16 OA0 = {}, OA1 = {}, OB0 = {}, OB1 = {};

  // staging: K 4 passes (32 rows each), V 4 passes (16 rows each)
  const int krow = t >> 3;                        // 0..31 (+p*32)
  const int kcb  = (t & 7) ^ (krow & 7);          // 8-block swizzle (64 cols)
  const int vrow = t >> 4;                        // 0..15 (+p*16)
  const int vcb  = (t & 15) ^ vrow;               // 16-block swizzle (128 cols)
  const u16* ksrc = Kbh + (size_t)krow*64 + kcb*8;
  const u16* vsrc = Vbh + (size_t)vrow*N_ + vcb*8;

  auto stage = [&](int buf, int kv) {
#pragma unroll
    for (int p = 0; p < 4; ++p)
      gload16(ksrc + (size_t)(kv + p*32)*64, &Klds[buf][(p*256 + t)*8]);
#pragma unroll
    for (int p = 0; p < 4; ++p)
      gload16(vsrc + kv + (size_t)(p*16)*N_, &Vlds[buf][(p*256 + t)*8]);
  };

  const int l7 = l31 & 7;
  const int l15 = l31 & 15;

  stage(0, 0);
  __syncthreads();
  int cur = 0;

  for (int kv0 = 0; kv0 < N_; kv0 += 128) {
    if (kv0 + 128 < N_) stage(cur ^ 1, kv0 + 128);

#pragma unroll
    for (int c = 0; c < 2; ++c) {
      const int kb = c * 64;
      // K fragments once, reused for both q-halves
      bf16x8 kf0[4], kf1[4];
#pragma unroll
      for (int dd = 0; dd < 4; ++dd) {
        int cb = ((dd*2 + h) ^ l7) * 8;
        kf0[dd] = *(const bf16x8*)&Klds[cur][(kb + l31)*64 + cb];
        kf1[dd] = *(const bf16x8*)&Klds[cur][(kb + 32 + l31)*64 + cb];
      }
      // V fragments hoisted: lgkmcnt overlaps QK MFMA issue
      bf16x8 vf0[4], vf1[4];
#pragma unroll
      for (int ks = 0; ks < 4; ++ks) {
        int kc = (c*8 + ks*2 + h) ^ l15;
        vf0[ks] = *(const bf16x8*)&Vlds[cur][l31*128 + kc*8];
        vf1[ks] = *(const bf16x8*)&Vlds[cur][(32 + l31)*128 + kc*8];
      }

      f32x16 SA0 = {}, SA1 = {}, SB0 = {}, SB1 = {};
#pragma unroll
      for (int dd = 0; dd < 4; ++dd) {
        SA0 = __builtin_amdgcn_mfma_f32_32x32x16_bf16(kf0[dd], qfA[dd], SA0, 0, 0, 0);
        SA1 = __builtin_amdgcn_mfma_f32_32x32x16_bf16(kf1[dd], qfA[dd], SA1, 0, 0, 0);
      }
#pragma unroll
      for (int dd = 0; dd < 4; ++dd) {
        SB0 = __builtin_amdgcn_mfma_f32_32x32x16_bf16(kf0[dd], qfB[dd], SB0, 0, 0, 0);
        SB1 = __builtin_amdgcn_mfma_f32_32x32x16_bf16(kf1[dd], qfB[dd], SB1, 0, 0, 0);
      }

      // half A: exp2 direct (no max), build P frags
      exp2v(SA0); exp2v(SA1);
      bf16x8 pfA[4];
      buildP(SA0, &pfA[0]);
      buildP(SA1, &pfA[2]);

#pragma unroll
      for (int ks = 0; ks < 4; ++ks) {
        OA0 = __builtin_amdgcn_mfma_f32_32x32x16_bf16(vf0[ks], pfA[ks], OA0, 0, 0, 0);
        OA1 = __builtin_amdgcn_mfma_f32_32x32x16_bf16(vf1[ks], pfA[ks], OA1, 0, 0, 0);
      }
      lA = pk_add(lA, sumtree(SA0, SA1));   // after PV-A issue

      // half B
      exp2v(SB0); exp2v(SB1);
      bf16x8 pfB[4];
      buildP(SB0, &pfB[0]);
      buildP(SB1, &pfB[2]);
#pragma unroll
      for (int ks = 0; ks < 4; ++ks) {
        OB0 = __builtin_amdgcn_mfma_f32_32x32x16_bf16(vf0[ks], pfB[ks], OB0, 0, 0, 0);
        OB1 = __builtin_amdgcn_mfma_f32_32x32x16_bf16(vf1[ks], pfB[ks], OB1, 0, 0, 0);
      }
      lB = pk_add(lB, sumtree(SB0, SB1));
    }

    __syncthreads();   // all waves done with [cur]; prefetch landed
    cur ^= 1;
  }

  // epilogue: per-half l combine + write ctx [B,N,D] bf16
  int b = bh >> 4, hh = bh & 15;
  {
    float lps = lA.x + lA.y;
    i32x2 lsw = pl32swap(__float_as_uint(lps), __float_as_uint(lps));
    float ltot = __uint_as_float((unsigned)lsw.x) + __uint_as_float((unsigned)lsw.y);
    float linv = __builtin_amdgcn_rcpf(ltot);
    f32x2 li2; li2.x = linv; li2.y = linv;
    unsigned* crow = (unsigned*)(ctx + ((size_t)b*N_ + (q0 + l31))*D_ + hh*64);
#pragma unroll
    for (int rp = 0; rp < 8; ++rp) {
      int r = rp*2;
      int d0 = (r & 3) + 8*(r >> 2) + 4*h;
      f32x2 o0 = pk_mul(sp2(OA0, rp), li2);
      f32x2 o1 = pk_mul(sp2(OA1, rp), li2);
      crow[d0 >> 1]        = cvt_pk(o0.x, o0.y);
      crow[(d0 + 32) >> 1] = cvt_pk(o1.x, o1.y);
    }
  }
  {
    float lps = lB.x + lB.y;
    i32x2 lsw = pl32swap(__float_as_uint(lps), __float_as_uint(lps));
    float ltot = __uint_as_float((unsigned)lsw.x) + __uint_as_float((unsigned)lsw.y);
    float linv = __builtin_amdgcn_rcpf(ltot);
    f32x2 li2; li2.x = linv; li2.y = linv;
    unsigned* crow = (unsigned*)(ctx + ((size_t)b*N_ + (q0 + 32 + l31))*D_ + hh*64);
#pragma unroll
    for (int rp = 0; rp < 8; ++rp) {
      int r = rp*2;
      int d0 = (r & 3) + 8*(r >> 2) + 4*h;
      f32x2 o0 = pk_mul(sp2(OB0, rp), li2);
      f32x2 o1 = pk_mul(sp2(OB1, rp), li2);
      crow[d0 >> 1]        = cvt_pk(o0.x, o0.y);
      crow[(d0 + 32) >> 1] = cvt_pk(o1.x, o1.y);
    }
  }
}

// ---------------- LayerNorm in-place on d_out ----------------
__global__ __launch_bounds__(256) void ln_fwd(float* __restrict__ io,
    const float* __restrict__ gamma, const float* __restrict__ beta)
{
  __shared__ float red[4];
  const int t = threadIdx.x;
  const int lane = t & 63, w = t >> 6;
  float4* row = (float4*)(io + (size_t)blockIdx.x * 1024);
  float4 x = row[t];
  float s = x.x + x.y + x.z + x.w;
#pragma unroll
  for (int m = 1; m < 64; m <<= 1) s += __shfl_xor(s, m);
  if (lane == 0) red[w] = s;
  __syncthreads();
  float mean = (red[0] + red[1] + red[2] + red[3]) * (1.f/1024.f);
  __syncthreads();
  float dx0 = x.x - mean, dx1 = x.y - mean, dx2 = x.z - mean, dx3 = x.w - mean;
  float sq = dx0*dx0 + dx1*dx1 + dx2*dx2 + dx3*dx3;
#pragma unroll
  for (int m = 1; m < 64; m <<= 1) sq += __shfl_xor(sq, m);
  if (lane == 0) red[w] = sq;
  __syncthreads();
  float var = (red[0] + red[1] + red[2] + red[3]) * (1.f/1024.f);
  float rstd = rsqrtf(var + 1e-5f);
  float4 g = ((const float4*)gamma)[t];
  float4 bb = ((const float4*)beta)[t];
  float4 y;
  y.x = dx0*rstd*g.x + bb.x;
  y.y = dx1*rstd*g.y + bb.y;
  y.z = dx2*rstd*g.z + bb.z;
  y.w = dx3*rstd*g.w + bb.w;
  row[t] = y;
}

extern "C" void kernel_launch(void* const* d_in, const int* in_sizes, int n_in,
                              void* d_out, int out_size, void* d_ws, size_t ws_size,
                              hipStream_t stream) {
  const float* q     = (const float*)d_in[0];
  const float* k     = (const float*)d_in[1];
  const float* v     = (const float*)d_in[2];
  const float* Wq    = (const float*)d_in[3];
  const float* Wk    = (const float*)d_in[4];
  const float* Wv    = (const float*)d_in[5];
  const float* Wo    = (const float*)d_in[6];
  const float* gamma = (const float*)d_in[7];
  const float* beta  = (const float*)d_in[8];
  float* out = (float*)d_out;

  char* ws = (char*)d_ws;
  const size_t MB = 1024*1024;
  u16* Wqb = (u16*)(ws + 0*MB);    // 2 MB each
  u16* Wkb = (u16*)(ws + 2*MB);
  u16* Wvb = (u16*)(ws + 4*MB);
  u16* Wob = (u16*)(ws + 6*MB);
  u16* Qs  = (u16*)(ws + 8*MB);    // [B,H,N,Dh] bf16 (pre-scaled by QSCALE)
  u16* Ks  = (u16*)(ws + 24*MB);   // [B,H,N,Dh]
  u16* VTs = (u16*)(ws + 40*MB);   // [B,H,Dh,N]
  u16* ctx = (u16*)(ws + 56*MB);   // [B,N,D] bf16

  const int nw4 = 4*((D_*D_)/4);   // 1M float4s
  cast_w<<<nw4/256, 256, 0, stream>>>(Wq, Wk, Wv, Wo, Wqb, Wkb, Wvb, Wob);

  dim3 gproj(M_/128, D_/128, 3);   // (64, 8, 3)
  gemm_qkv<<<gproj, 256, 0, stream>>>(q, k, v, Wqb, Wkb, Wvb, Qs, Ks, VTs);

  flash_attn<<<dim3(B_*H_, N_/256), 256, 0, stream>>>(Qs, Ks, VTs, ctx);

  gemm_out<<<dim3(M_/128, D_/128), 256, 0, stream>>>(ctx, Wob, q, out);

  ln_fwd<<<M_, 256, 0, stream>>>(out, gamma, beta);
}